// Round 4
// baseline (178.592 us; speedup 1.0000x reference)
//
#include <hip/hip_runtime.h>

// Problem constants
#define B_  32
#define M_  64
#define K_  36
#define DS_ 512
#define DX_ 128
#define DQ_ 512
#define H_  256

#define TMA 8    // rows of s2 per block in kernA

// ---------------------------------------------------------------------------
// Kernel A (grid = 544, block = 512 threads, in-block split-K, no atomics):
//  blocks 0..511: tile = bid>>1 (8 rows of s2), mat = bid&1.
//    thread (ks = t>>8, h = t&255) computes a K=256 partial of
//      (mat ? ph1 : pre_s)[r,h] = sum_d s2[r,d]*W[d,h]
//    ks=1 partials go through LDS; ks=0 adds and stores. s2 accessed with
//    block-uniform indices -> scalar (s_load) path.
//  blocks 512..543: qpre[b,h] = sum_d q[b,d]*w_q[d,h] + score_b1[h]
// ---------------------------------------------------------------------------
__global__ __launch_bounds__(512) void kernA(
    const float* __restrict__ s2,        // (2048,512)
    const float* __restrict__ score_w1,  // (1152,256)
    const float* __restrict__ h_w1,      // (512,256)
    const float* __restrict__ q,         // (B,512)
    const float* __restrict__ score_b1,  // (256)
    float* __restrict__ pre_s,           // (2048,256)
    float* __restrict__ ph1,             // (2048,256)
    float* __restrict__ qpre)            // (B,256)
{
    __shared__ float lsum[TMA][H_];      // 8 KB
    const int t   = threadIdx.x;
    const int bid = blockIdx.x;

    if (bid >= 512) {                    // ---- qpre blocks ----
        if (t < H_) {
            const int b = bid - 512;
            const float* qp = q + (size_t)b * DQ_;       // block-uniform
            const float* wq = score_w1 + (size_t)(DS_ + DX_) * H_ + t;
            float a0 = score_b1[t], a1 = 0.f, a2 = 0.f, a3 = 0.f;
            for (int d = 0; d < DQ_; d += 4) {
                const float4 q4 = *(const float4*)(qp + d);  // scalar load
                a0 = fmaf(q4.x, wq[(size_t)(d + 0) * H_], a0);
                a1 = fmaf(q4.y, wq[(size_t)(d + 1) * H_], a1);
                a2 = fmaf(q4.z, wq[(size_t)(d + 2) * H_], a2);
                a3 = fmaf(q4.w, wq[(size_t)(d + 3) * H_], a3);
            }
            qpre[(size_t)b * H_ + t] = (a0 + a1) + (a2 + a3);
        }
        return;
    }

    const int tile = bid >> 1;
    const int mat  = bid & 1;
    const int ks   = t >> 8;             // K-half: 0 or 1
    const int h    = t & (H_ - 1);

    const float* w  = (mat ? h_w1 : score_w1) + (size_t)(ks * 256) * H_ + h;
    const float* sp = s2 + (size_t)tile * TMA * DS_ + ks * 256;  // block-uniform

    float acc[TMA];
    #pragma unroll
    for (int i = 0; i < TMA; ++i) acc[i] = 0.f;

    #pragma unroll 4
    for (int d = 0; d < 256; d += 4) {
        const float w0 = w[(size_t)(d + 0) * H_];
        const float w1 = w[(size_t)(d + 1) * H_];
        const float w2v = w[(size_t)(d + 2) * H_];
        const float w3 = w[(size_t)(d + 3) * H_];
        #pragma unroll
        for (int i = 0; i < TMA; ++i) {
            const float4 s4 = *(const float4*)(sp + (size_t)i * DS_ + d); // s_load_dwordx4
            acc[i] = fmaf(s4.x, w0, acc[i]);
            acc[i] = fmaf(s4.y, w1, acc[i]);
            acc[i] = fmaf(s4.z, w2v, acc[i]);
            acc[i] = fmaf(s4.w, w3, acc[i]);
        }
    }

    if (ks) {
        #pragma unroll
        for (int i = 0; i < TMA; ++i) lsum[i][h] = acc[i];
    }
    __syncthreads();
    if (!ks) {
        float* dst = (mat ? ph1 : pre_s) + (size_t)tile * TMA * H_ + h;
        #pragma unroll
        for (int i = 0; i < TMA; ++i)
            dst[(size_t)i * H_] = acc[i] + lsum[i][h];
    }
}

// ---------------------------------------------------------------------------
// Kernel C: one block per (b,k).
//   cw[h]    = qpre[b,h] + sum_d x0[b,k,d]*w_x[d,h]
//   logit[m] = sum_h relu(pre_s[b,m,h] + cw[h]) * w2[h]   (LDS transpose
//              reduce: red[m][lane] partials, wave0 folds lanes + softmax)
//   ragg[h]  = sum_m att[m] * relu(ph1[b,m,h] + h_b1[h])
//   out[b,k,128:256] = ragg . h_w2 + h_b2 ;  out[b,k,0:128] = x0[b,k,:]
// ---------------------------------------------------------------------------
__global__ __launch_bounds__(256) void kernC(
    const float* __restrict__ pre_s,     // (2048,256)
    const float* __restrict__ ph1,       // (2048,256)
    const float* __restrict__ qpre,      // (B,256)
    const float* __restrict__ score_w1,  // (1152,256)
    const float* __restrict__ score_w2,  // (256,1)
    const float* __restrict__ h_b1,      // (256)
    const float* __restrict__ h_w2,      // (256,128)
    const float* __restrict__ h_b2,      // (128)
    const float* __restrict__ x0,        // (B*K,128)
    float* __restrict__ out)             // (B*K,256)
{
    __shared__ float red[M_][65];        // 16.6 KB, padded: conflict-free
    __shared__ float cw[H_];             // reused later as ragg
    __shared__ float w2s[H_];
    __shared__ float att[M_];
    __shared__ float part[DX_];

    const int t  = threadIdx.x;
    const int bk = blockIdx.x;           // 0..1151
    const int b  = bk / K_;
    const float* x0p = x0 + (size_t)bk * DX_;   // block-uniform base

    w2s[t] = score_w2[t];
    // cw = qpre[b] + x0[b,k] . w_x   (x0 via scalar loads, 4-way ILP)
    {
        const float* wx = score_w1 + (size_t)DS_ * H_ + t;
        float a0 = qpre[(size_t)b * H_ + t], a1 = 0.f, a2 = 0.f, a3 = 0.f;
        for (int d = 0; d < DX_; d += 4) {
            const float4 x4 = *(const float4*)(x0p + d);   // scalar load
            a0 = fmaf(x4.x, wx[(size_t)(d + 0) * H_], a0);
            a1 = fmaf(x4.y, wx[(size_t)(d + 1) * H_], a1);
            a2 = fmaf(x4.z, wx[(size_t)(d + 2) * H_], a2);
            a3 = fmaf(x4.w, wx[(size_t)(d + 3) * H_], a3);
        }
        cw[t] = (a0 + a1) + (a2 + a3);
    }
    __syncthreads();

    const int wave = t >> 6, lane = t & 63;
    const float c0 = cw[lane],        c1 = cw[lane + 64],
                c2 = cw[lane + 128],  c3 = cw[lane + 192];
    const float v0 = w2s[lane],       v1 = w2s[lane + 64],
                v2 = w2s[lane + 128], v3 = w2s[lane + 192];

    // phase 1: per-(m,lane) partials (no cross-lane ops, pure ILP)
    const float* ps = pre_s + (size_t)b * M_ * H_;
    #pragma unroll 4
    for (int mi = 0; mi < M_ / 4; ++mi) {
        const int m = wave * (M_ / 4) + mi;
        const float* p = ps + (size_t)m * H_;
        red[m][lane] = fmaxf(p[lane]       + c0, 0.f) * v0
                     + fmaxf(p[lane + 64]  + c1, 0.f) * v1
                     + fmaxf(p[lane + 128] + c2, 0.f) * v2
                     + fmaxf(p[lane + 192] + c3, 0.f) * v3;
    }
    __syncthreads();

    // phase 2 + softmax: wave 0, lane = m
    if (wave == 0) {
        float a0 = 0.f, a1 = 0.f, a2 = 0.f, a3 = 0.f;
        #pragma unroll 4
        for (int l = 0; l < 64; l += 4) {
            a0 += red[lane][l + 0];
            a1 += red[lane][l + 1];
            a2 += red[lane][l + 2];
            a3 += red[lane][l + 3];
        }
        const float L = (a0 + a1) + (a2 + a3);   // logit[m=lane]
        float mx = L;                            // softmax (score_b2 cancels)
        #pragma unroll
        for (int off = 32; off > 0; off >>= 1)
            mx = fmaxf(mx, __shfl_xor(mx, off, 64));
        const float e = expf(L - mx);
        float s = e;
        #pragma unroll
        for (int off = 32; off > 0; off >>= 1)
            s += __shfl_xor(s, off, 64);
        att[lane] = e / s;
    }
    __syncthreads();

    // ragg[h=t] = sum_m att[m] * relu(ph1[b,m,t] + h_b1[t])   (coalesced)
    {
        const float* hp = ph1 + (size_t)b * M_ * H_ + t;
        const float b1v = h_b1[t];
        float r0 = 0.f, r1 = 0.f;
        #pragma unroll 4
        for (int m = 0; m < M_; m += 2) {
            r0 = fmaf(att[m],     fmaxf(hp[(size_t)m * H_] + b1v, 0.f), r0);
            r1 = fmaf(att[m + 1], fmaxf(hp[(size_t)(m + 1) * H_] + b1v, 0.f), r1);
        }
        cw[t] = r0 + r1;               // cw now holds ragg
    }
    __syncthreads();

    // out[128:256] = ragg . h_w2 + h_b2, split-K across thread halves
    const int f  = t & 127;
    const int hh = t >> 7;             // 0 or 1 -> h-range [hh*128, hh*128+128)
    const float* wp = h_w2 + (size_t)(hh * 128) * DX_ + f;
    float a0 = 0.f, a1 = 0.f, a2 = 0.f, a3 = 0.f;
    for (int hcv = 0; hcv < 128; hcv += 4) {
        a0 = fmaf(cw[hh * 128 + hcv + 0], wp[(size_t)(hcv + 0) * DX_], a0);
        a1 = fmaf(cw[hh * 128 + hcv + 1], wp[(size_t)(hcv + 1) * DX_], a1);
        a2 = fmaf(cw[hh * 128 + hcv + 2], wp[(size_t)(hcv + 2) * DX_], a2);
        a3 = fmaf(cw[hh * 128 + hcv + 3], wp[(size_t)(hcv + 3) * DX_], a3);
    }
    const float sum = (a0 + a1) + (a2 + a3);
    if (hh) part[f] = sum;
    __syncthreads();

    float* o = out + (size_t)bk * (2 * DX_);
    if (!hh) {
        o[DX_ + f] = sum + part[f] + h_b2[f];
    } else {
        o[f] = x0p[f];                 // per-lane coalesced passthrough
    }
}

extern "C" void kernel_launch(void* const* d_in, const int* in_sizes, int n_in,
                              void* d_out, int out_size, void* d_ws, size_t ws_size,
                              hipStream_t stream) {
    (void)in_sizes; (void)n_in; (void)out_size; (void)ws_size;
    const float* s2       = (const float*)d_in[0];
    const float* x0       = (const float*)d_in[1];
    const float* q        = (const float*)d_in[2];
    const float* score_w1 = (const float*)d_in[3];
    const float* score_b1 = (const float*)d_in[4];
    const float* score_w2 = (const float*)d_in[5];
    // d_in[6] = score_b2 (cancels in softmax)
    const float* h_w1     = (const float*)d_in[7];
    const float* h_b1     = (const float*)d_in[8];
    const float* h_w2     = (const float*)d_in[9];
    const float* h_b2     = (const float*)d_in[10];
    float* out = (float*)d_out;

    float* ws    = (float*)d_ws;
    float* pre_s = ws;                                 // 2048*256
    float* ph1   = ws + (size_t)B_ * M_ * H_;          // 2048*256
    float* qpre  = ph1 + (size_t)B_ * M_ * H_;         // 32*256

    kernA<<<544, 512, 0, stream>>>(s2, score_w1, h_w1, q, score_b1,
                                   pre_s, ph1, qpre);
    kernC<<<B_ * K_, 256, 0, stream>>>(pre_s, ph1, qpre, score_w1, score_w2,
                                       h_b1, h_w2, h_b2, x0, out);
}

// Round 5
// 139.525 us; speedup vs baseline: 1.2800x; 1.2800x over previous
//
#include <hip/hip_runtime.h>

// Problem constants
#define B_  32
#define M_  64
#define K_  36
#define DS_ 512
#define DX_ 128
#define DQ_ 512
#define H_  256

#define TMA  16     // rows of s2 per GEMM block in kernA
#define DCH  128    // d-chunk (split-K factor 4)
#define KB   9      // k's per cvec block

// ---------------------------------------------------------------------------
// Kernel A (grid = 1152, block = 256, no LDS):
//  blocks 0..1023: tile = bid>>3 (16 rows), mat = bid&1, dq = (bid>>1)&3.
//    atomicAdd partial GEMM: (mat?ph1:pre_s)[r,h] += sum_{d in chunk} s2[r,d]*W[d,h]
//    s2 accessed with block-uniform indices -> scalar (s_load) path.
//  blocks 1024..1151: cvec[b,k,h] = q[b]·w_q + x0[b,k]·w_x + score_b1
//    (b = cb>>2, k = (cb&3)*9 .. +8)
// ---------------------------------------------------------------------------
__global__ __launch_bounds__(256) void kernA(
    const float* __restrict__ s2,        // (2048,512)
    const float* __restrict__ score_w1,  // (1152,256)
    const float* __restrict__ h_w1,      // (512,256)
    const float* __restrict__ q,         // (B,512)
    const float* __restrict__ score_b1,  // (256)
    const float* __restrict__ x0,        // (B*K,128)
    float* __restrict__ pre_s,           // (2048,256)  zero-init
    float* __restrict__ ph1,             // (2048,256)  zero-init
    float* __restrict__ cvec)            // (B*K,256)
{
    const int t   = threadIdx.x;
    const int bid = blockIdx.x;

    if (bid >= 1024) {                   // ---- cvec blocks ----
        const int cb = bid - 1024;
        const int b  = cb >> 2;
        const int kq = cb & 3;
        // q . w_q  (q via block-uniform scalar loads)
        const float* qp = q + (size_t)b * DQ_;
        const float* wq = score_w1 + (size_t)(DS_ + DX_) * H_ + t;
        float a0 = score_b1[t], a1 = 0.f, a2 = 0.f, a3 = 0.f;
        for (int d = 0; d < DQ_; d += 4) {
            const float4 q4 = *(const float4*)(qp + d);      // s_load
            a0 = fmaf(q4.x, wq[(size_t)(d + 0) * H_], a0);
            a1 = fmaf(q4.y, wq[(size_t)(d + 1) * H_], a1);
            a2 = fmaf(q4.z, wq[(size_t)(d + 2) * H_], a2);
            a3 = fmaf(q4.w, wq[(size_t)(d + 3) * H_], a3);
        }
        const float qacc = (a0 + a1) + (a2 + a3);

        float acc[KB];
        #pragma unroll
        for (int kk = 0; kk < KB; ++kk) acc[kk] = qacc;

        const float* xsrc = x0 + ((size_t)b * K_ + kq * KB) * DX_;
        const float* wx   = score_w1 + (size_t)DS_ * H_ + t;
        for (int d = 0; d < DX_; d += 4) {
            const float w0 = wx[(size_t)(d + 0) * H_];
            const float w1 = wx[(size_t)(d + 1) * H_];
            const float w2v = wx[(size_t)(d + 2) * H_];
            const float w3 = wx[(size_t)(d + 3) * H_];
            #pragma unroll
            for (int kk = 0; kk < KB; ++kk) {
                const float4 x4 = *(const float4*)(xsrc + (size_t)kk * DX_ + d);
                acc[kk] = fmaf(x4.x, w0, acc[kk]);
                acc[kk] = fmaf(x4.y, w1, acc[kk]);
                acc[kk] = fmaf(x4.z, w2v, acc[kk]);
                acc[kk] = fmaf(x4.w, w3, acc[kk]);
            }
        }
        #pragma unroll
        for (int kk = 0; kk < KB; ++kk)
            cvec[((size_t)b * K_ + kq * KB + kk) * H_ + t] = acc[kk];
        return;
    }

    const int tile = bid >> 3;
    const int mat  = bid & 1;
    const int dq   = (bid >> 1) & 3;

    const float* w  = (mat ? h_w1 : score_w1) + (size_t)(dq * DCH) * H_ + t;
    const float* sp = s2 + (size_t)tile * TMA * DS_ + dq * DCH;  // block-uniform

    float acc[TMA];
    #pragma unroll
    for (int i = 0; i < TMA; ++i) acc[i] = 0.f;

    for (int d = 0; d < DCH; d += 4) {
        const float w0 = w[(size_t)(d + 0) * H_];
        const float w1 = w[(size_t)(d + 1) * H_];
        const float w2v = w[(size_t)(d + 2) * H_];
        const float w3 = w[(size_t)(d + 3) * H_];
        #pragma unroll
        for (int i = 0; i < TMA; ++i) {
            const float4 s4 = *(const float4*)(sp + (size_t)i * DS_ + d); // s_load_dwordx4
            acc[i] = fmaf(s4.x, w0, acc[i]);
            acc[i] = fmaf(s4.y, w1, acc[i]);
            acc[i] = fmaf(s4.z, w2v, acc[i]);
            acc[i] = fmaf(s4.w, w3, acc[i]);
        }
    }

    float* dst = (mat ? ph1 : pre_s) + (size_t)tile * TMA * H_ + t;
    #pragma unroll
    for (int i = 0; i < TMA; ++i)
        atomicAdd(dst + (size_t)i * H_, acc[i]);
}

// ---------------------------------------------------------------------------
// Kernel H (grid = 1024, block = 256): h_s = relu(ph1 + h_b1) . h_w2
//   tile = bid>>1 (4 rows), hh = bid&1 (h-half). Partial K=128 GEMM,
//   atomicAdd into zeroed h_s. (h_b2 deferred to kernC: sum(att)=1.)
// ---------------------------------------------------------------------------
__global__ __launch_bounds__(256) void kernH(
    const float* __restrict__ ph1,       // (2048,256)
    const float* __restrict__ h_b1,      // (256)
    const float* __restrict__ h_w2,      // (256,128)
    float* __restrict__ h_s)             // (2048,128)  zero-init
{
    __shared__ float sh[4][DCH];         // 2 KB: relu'd activations
    const int t    = threadIdx.x;
    const int tile = blockIdx.x >> 1;
    const int hh   = blockIdx.x & 1;
    const int r0   = tile * 4;

    if (t < 128) {                       // stage 4 rows x 128 h (float4)
        const int row = t >> 5, j4 = (t & 31) * 4;
        const float4 p = *(const float4*)(ph1 + (size_t)(r0 + row) * H_ + hh * DCH + j4);
        const float4 b = *(const float4*)(h_b1 + hh * DCH + j4);
        float4 r;
        r.x = fmaxf(p.x + b.x, 0.f);
        r.y = fmaxf(p.y + b.y, 0.f);
        r.z = fmaxf(p.z + b.z, 0.f);
        r.w = fmaxf(p.w + b.w, 0.f);
        *(float4*)&sh[row][j4] = r;
    }
    __syncthreads();

    const int f  = t & 127;
    const int rp = t >> 7;               // 0 -> rows 0,1 ; 1 -> rows 2,3
    const float* wp = h_w2 + (size_t)(hh * DCH) * DX_ + f;
    float acc0 = 0.f, acc1 = 0.f;
    #pragma unroll 4
    for (int h = 0; h < DCH; ++h) {
        const float wv = wp[(size_t)h * DX_];
        acc0 = fmaf(sh[rp * 2 + 0][h], wv, acc0);
        acc1 = fmaf(sh[rp * 2 + 1][h], wv, acc1);
    }
    atomicAdd(h_s + (size_t)(r0 + rp * 2 + 0) * DX_ + f, acc0);
    atomicAdd(h_s + (size_t)(r0 + rp * 2 + 1) * DX_ + f, acc1);
}

// ---------------------------------------------------------------------------
// Kernel C: one block per (b,k).
//   logit[m] = sum_h relu(pre_s[b,m,h] + cvec[b,k,h]) * w2[h]
//     (float4 loads; LDS-transpose reduce; wave0 folds + softmax)
//   out[b,k,128:256] = sum_m att[m]*h_s[b,m,:] + h_b2 ; out[b,k,0:128] = x0
// ---------------------------------------------------------------------------
__global__ __launch_bounds__(256) void kernC(
    const float* __restrict__ pre_s,     // (2048,256)
    const float* __restrict__ h_s,       // (2048,128)
    const float* __restrict__ cvec,      // (B*K,256)
    const float* __restrict__ score_w2,  // (256,1)
    const float* __restrict__ h_b2,      // (128)
    const float* __restrict__ x0,        // (B*K,128)
    float* __restrict__ out)             // (B*K,256)
{
    __shared__ float  red[M_][65];       // padded: conflict-free transpose
    __shared__ float  att[M_];
    __shared__ float4 part[8][32];

    const int t    = threadIdx.x;
    const int bk   = blockIdx.x;         // 0..1151
    const int b    = bk / K_;
    const int wave = t >> 6, lane = t & 63;

    // per-lane h-quad constants (coalesced global reads, L2-hot)
    const float4 cf = *(const float4*)(cvec + (size_t)bk * H_ + 4 * lane);
    const float4 wf = *(const float4*)(score_w2 + 4 * lane);

    // phase 1: red[m][lane] = sum over this lane's 4 h's
    const float* ps = pre_s + (size_t)b * M_ * H_;
    #pragma unroll 4
    for (int mi = 0; mi < M_ / 4; ++mi) {
        const int m = wave * (M_ / 4) + mi;
        const float4 p = *(const float4*)(ps + (size_t)m * H_ + 4 * lane);
        red[m][lane] = fmaxf(p.x + cf.x, 0.f) * wf.x
                     + fmaxf(p.y + cf.y, 0.f) * wf.y
                     + fmaxf(p.z + cf.z, 0.f) * wf.z
                     + fmaxf(p.w + cf.w, 0.f) * wf.w;
    }
    __syncthreads();

    // phase 2 + softmax: wave 0, lane = m
    if (wave == 0) {
        float a0 = 0.f, a1 = 0.f, a2 = 0.f, a3 = 0.f;
        #pragma unroll 4
        for (int l = 0; l < 64; l += 4) {
            a0 += red[lane][l + 0];
            a1 += red[lane][l + 1];
            a2 += red[lane][l + 2];
            a3 += red[lane][l + 3];
        }
        const float L = (a0 + a1) + (a2 + a3);   // logit[m=lane]
        float mx = L;                            // softmax (score_b2 cancels)
        #pragma unroll
        for (int off = 32; off > 0; off >>= 1)
            mx = fmaxf(mx, __shfl_xor(mx, off, 64));
        const float e = expf(L - mx);
        float s = e;
        #pragma unroll
        for (int off = 32; off > 0; off >>= 1)
            s += __shfl_xor(s, off, 64);
        att[lane] = e / s;
    }
    __syncthreads();

    // agg: group g (8 m's), f-quad l32
    {
        const int g = t >> 5, l32 = t & 31;
        const float* hp = h_s + ((size_t)b * M_ + g * 8) * DX_ + 4 * l32;
        float4 acc = make_float4(0.f, 0.f, 0.f, 0.f);
        #pragma unroll
        for (int j = 0; j < 8; ++j) {
            const float a = att[g * 8 + j];
            const float4 hv = *(const float4*)(hp + (size_t)j * DX_);
            acc.x = fmaf(a, hv.x, acc.x);
            acc.y = fmaf(a, hv.y, acc.y);
            acc.z = fmaf(a, hv.z, acc.z);
            acc.w = fmaf(a, hv.w, acc.w);
        }
        part[g][l32] = acc;
    }
    __syncthreads();

    const float4* x04 = (const float4*)(x0 + (size_t)bk * DX_);
    float4* o4 = (float4*)(out + (size_t)bk * 2 * DX_);
    if (t < 32) {
        float4 s = part[0][t];
        #pragma unroll
        for (int j = 1; j < 8; ++j) {
            const float4 p = part[j][t];
            s.x += p.x; s.y += p.y; s.z += p.z; s.w += p.w;
        }
        const float4 b2 = *(const float4*)(h_b2 + 4 * t);
        s.x += b2.x; s.y += b2.y; s.z += b2.z; s.w += b2.w;
        o4[32 + t] = s;
    } else if (t < 64) {
        o4[t - 32] = x04[t - 32];        // x0 passthrough
    }
}

extern "C" void kernel_launch(void* const* d_in, const int* in_sizes, int n_in,
                              void* d_out, int out_size, void* d_ws, size_t ws_size,
                              hipStream_t stream) {
    (void)in_sizes; (void)n_in; (void)out_size; (void)ws_size;
    const float* s2       = (const float*)d_in[0];
    const float* x0       = (const float*)d_in[1];
    const float* q        = (const float*)d_in[2];
    const float* score_w1 = (const float*)d_in[3];
    const float* score_b1 = (const float*)d_in[4];
    const float* score_w2 = (const float*)d_in[5];
    // d_in[6] = score_b2 (cancels in softmax)
    const float* h_w1     = (const float*)d_in[7];
    const float* h_b1     = (const float*)d_in[8];
    const float* h_w2     = (const float*)d_in[9];
    const float* h_b2     = (const float*)d_in[10];
    float* out = (float*)d_out;

    float* ws    = (float*)d_ws;
    float* pre_s = ws;                                 // 2048*256
    float* ph1   = pre_s + (size_t)B_ * M_ * H_;       // 2048*256
    float* h_s   = ph1   + (size_t)B_ * M_ * H_;       // 2048*128
    float* cvec  = h_s   + (size_t)B_ * M_ * DX_;      // 1152*256

    // zero atomic accumulators: pre_s + ph1 + h_s = 5.24 MB
    hipMemsetAsync(d_ws, 0,
                   (size_t)B_ * M_ * (H_ + H_ + DX_) * sizeof(float), stream);

    kernA<<<1152, 256, 0, stream>>>(s2, score_w1, h_w1, q, score_b1, x0,
                                    pre_s, ph1, cvec);
    kernH<<<1024, 256, 0, stream>>>(ph1, h_b1, h_w2, h_s);
    kernC<<<B_ * K_, 256, 0, stream>>>(pre_s, h_s, cvec, score_w2, h_b2,
                                       x0, out);
}